// Round 17
// baseline (31.463 us; speedup 1.0000x reference)
//
#include <hip/hip_runtime.h>

// PixelEffectModule: 8-bin intensity histogram over 11x11 windows at stride 8,
// argmax bin, output that bin's mean RGB, upsampled 8x8.
// Input: rgb (1,3,2048,2048) fp32 in [0,255). Output: (1,3,2048,2048) fp32.
//
// R17 = R14's green DMA-staged skeleton (16-cell span, 128-thread WG, 9 DMA
// iters, one __syncthreads drain, XCD swizzle) + SINGLE-PASS compute:
//  - quantized per-bin sums: 16-bit fields in u64 pairs (lo=bins 0-3,
//    hi=bins 4-7) per channel; field max 121*255=30855 < 65536. Final
//    value = field/count -> |err| <= 0.5 (R1 passed at 0.5; threshold 4.12).
//    Eliminates pass 2 (12 b128 re-reads + 2nd barrier reduce) and the
//    nibble cache.
//  - 8 cells x 8 parts PER WAVE (R15's verified mapping): wave w owns cells
//    w*8..w*8+7 of the staged span; full reduce = shfl_xor(8/16/32) on
//    7 u64s, in-register. ZERO barriers after the drain; no LDS reduce
//    scratch at all.
//  - per-quad processing (12 live floats) + 7 u64 accs ~= 45 live regs ->
//    fits the 64-VGPR allocator pin without spill (R6-R11 lesson).
// Tripwires: absmax > 1.0 -> quantization bug, revert; WRITE > 60 MB ->
// spill; dur >= 25 us -> plateau, assess roofline.

#define Wd 2048
#define HW (2048 * 2048)
#define CPR 34              // 16B chunks per staged row (136 floats)
#define CPC (11 * CPR)      // 374 chunks per channel
#define NCHK (3 * CPC)      // 1122 chunks per tile
#define PADC 1152           // padded chunk slots (9 iters x 128 threads)

typedef unsigned int u32;
typedef unsigned long long u64;
typedef float f32x4 __attribute__((ext_vector_type(4)));

// correctly-rounded t/3 (Markstein), 3 ops vs ~9-inst div expansion
__device__ __forceinline__ float div3(float t) {
    const float c = 0x1.555556p-2f;  // RN(1/3)
    float q0 = t * c;
    float r  = __builtin_fmaf(q0, -3.0f, t);
    return __builtin_fmaf(r, c, q0);
}

// chunk parity-flip swizzle (R16's, best measured): involution, range-safe
__device__ __forceinline__ u32 swz(u32 c) { return c ^ ((c >> 4) & 1u); }

__global__ __launch_bounds__(128, 4)
void pixel_effect_kernel(const float* __restrict__ rgb, float* __restrict__ out) {
    __shared__ float ldsf[PADC * 4];    // 18.4 KB staged tile (no other LDS)

    const int tid  = threadIdx.x;       // 0..127
    const int lane = tid & 63;
    const int w    = tid >> 6;          // wave 0..1 (owns 8 cells)
    const int p    = lane >> 3;         // row-band part 0..7
    const int cl   = lane & 7;          // cell within wave's 8-strip

    // XCD swizzle (grid 4096 = 8*512, bijective): XCD (wgid&7) owns slots
    // [512*xcd, 512*xcd+512) = 32 contiguous cell-rows.
    u32 wgid = blockIdx.x;
    u32 slot = (wgid & 7u) * 512u + (wgid >> 3);
    const int oy = (int)(slot >> 4);
    const int tx = (int)(slot & 15u);
    const int ox = tx * 16 + w * 8 + cl;

    const int xstart = tx ? (tx * 128 - 8) : 0;   // staged 136-float span
    const int ytop   = oy * 8 - 5;

    // ---- DMA stage: 1122 chunks global -> LDS (linear dest, pre-swz src) ----
#pragma unroll
    for (int it = 0; it < 9; ++it) {
        u32 cbase = (u32)it * 128u + (u32)(tid & ~63);  // wave-uniform
        u32 c = cbase + (u32)lane;
        c = c < (NCHK - 1) ? c : (NCHK - 1);            // clamp -> junk to pad
        u32 ch  = (c >= 2u * CPC) ? 2u : (c >= (u32)CPC ? 1u : 0u);
        u32 rem = c - ch * (u32)CPC;
        u32 row = rem / CPR;
        u32 wph = rem - row * CPR;                      // physical chunk-in-row
        u32 wlog = swz(wph);                            // logical chunk to fetch
        int y = ytop + (int)row; y = y < 0 ? 0 : y;     // clamped rows unread
        const float* gsrc = rgb + (size_t)ch * HW + (size_t)y * Wd
                          + (size_t)(xstart + (int)(wlog * 4u));
        float* ldst = &ldsf[cbase * 4u];                // wave-uniform base
        __builtin_amdgcn_global_load_lds(
            (const __attribute__((address_space(1))) void*)gsrc,
            (__attribute__((address_space(3))) void*)ldst, 16, 0, 0);
    }
    __syncthreads();   // single drain; ZERO barriers after this point

    // slot j maps row-local x = lx_off + j. Interior: j in [3,13]; ox==0:
    // j in [0,5]. 16-float read [lx_off, lx_off+16) always within the row.
    const int lx_off = (ox == 0) ? 0 : (8 * ox - 8 - xstart);  // mult of 8
    const int w0     = lx_off >> 2;                            // chunk index
    const u32 vmask  = (ox == 0) ? 0x003Fu : 0x3FF8u;
    const int rs = (p < 3) ? 2 * p : (3 + p);  // first window-row of this part
    const int nr = (p < 3) ? 2 : 1;            // rows: 2,2,2,1,1,1,1,1

    // ---- single pass: counts (8x u8 in u64) + quantized sums (16b fields) ----
    u64 cnt = 0;
    u64 loR = 0, hiR = 0, loG = 0, hiG = 0, loB = 0, hiB = 0;
#pragma unroll
    for (int k = 0; k < 2; ++k) {
        int r = rs + k;
        int y = ytop + r;                      // uniform per part-group
        if (k < nr && y >= 0) {
#pragma unroll
            for (int q = 0; q < 4; ++q) {      // per-quad: 12 live floats
                int rbR = (0 * 11 + r) * CPR;
                int rbG = (1 * 11 + r) * CPR;
                int rbB = (2 * 11 + r) * CPR;
                f32x4 r4 = *(const f32x4*)&ldsf[(u32)(rbR + swz(w0 + q)) * 4u];
                f32x4 g4 = *(const f32x4*)&ldsf[(u32)(rbG + swz(w0 + q)) * 4u];
                f32x4 b4 = *(const f32x4*)&ldsf[(u32)(rbB + swz(w0 + q)) * 4u];
#pragma unroll
                for (int jj = 0; jj < 4; ++jj) {
                    int j = 4 * q + jj;
                    float rr = r4[jj], gg = g4[jj], bb = b4[jj];
                    float m = div3(rr + gg + bb);
                    u32 bin = (u32)(m * 0.03125f);   // trunc(mean/32), exact
                    u32 valid = (vmask >> j) & 1u;
                    cnt += (u64)valid << (bin << 3);
                    u32 sh = (bin & 3u) << 4;        // field shift 0/16/32/48
                    bool vlo = valid && (bin < 4u);
                    bool vhi = valid && (bin >= 4u);
                    u64 qr = (u64)(u32)(rr + 0.5f) << sh;
                    u64 qg = (u64)(u32)(gg + 0.5f) << sh;
                    u64 qb = (u64)(u32)(bb + 0.5f) << sh;
                    loR += vlo ? qr : 0;  hiR += vhi ? qr : 0;
                    loG += vlo ? qg : 0;  hiG += vhi ? qg : 0;
                    loB += vlo ? qb : 0;  hiB += vhi ? qb : 0;
                }
            }
        }
    }

    // ---- full reduce across 8 parts, in-register (lane bits 3,4,5) ----
    cnt += __shfl_xor(cnt, 8);  cnt += __shfl_xor(cnt, 16);  cnt += __shfl_xor(cnt, 32);
    loR += __shfl_xor(loR, 8);  loR += __shfl_xor(loR, 16);  loR += __shfl_xor(loR, 32);
    hiR += __shfl_xor(hiR, 8);  hiR += __shfl_xor(hiR, 16);  hiR += __shfl_xor(hiR, 32);
    loG += __shfl_xor(loG, 8);  loG += __shfl_xor(loG, 16);  loG += __shfl_xor(loG, 32);
    hiG += __shfl_xor(hiG, 8);  hiG += __shfl_xor(hiG, 16);  hiG += __shfl_xor(hiG, 32);
    loB += __shfl_xor(loB, 8);  loB += __shfl_xor(loB, 16);  loB += __shfl_xor(loB, 32);
    hiB += __shfl_xor(hiB, 8);  hiB += __shfl_xor(hiB, 16);  hiB += __shfl_xor(hiB, 32);

    // ---- argmax bin, first-max wins (matches jnp.argmax) ----
    u32 lo = (u32)cnt, hi = (u32)(cnt >> 32);
    u32 best = 0, bc = lo & 0xFFu;
#pragma unroll
    for (int b = 1; b < 8; ++b) {
        u32 cb = ((b < 4 ? lo : hi) >> ((b & 3) * 8)) & 0xFFu;
        bool t = cb > bc;
        bc   = t ? cb : bc;
        best = t ? (u32)b : best;
    }

    // ---- select winning bin's quantized sums ----
    u32 sh2 = (best & 3u) << 4;
    u64 sRq = (best < 4u) ? loR : hiR;
    u64 sGq = (best < 4u) ? loG : hiG;
    u64 sBq = (best < 4u) ? loB : hiB;
    float fbc = (float)bc;
    float orv = (float)((u32)(sRq >> sh2) & 0xFFFFu) / fbc;
    float ogv = (float)((u32)(sGq >> sh2) & 0xFFFFu) / fbc;
    float obv = (float)((u32)(sBq >> sh2) & 0xFFFFu) / fbc;

    // ---- write: part p owns row p of the 8x8 block, 2x float4 per channel ----
    size_t base = (size_t)(oy * 8 + p) * Wd + (size_t)(ox * 8);
    float vals[3] = { orv, ogv, obv };
#pragma unroll
    for (int c = 0; c < 3; ++c) {
        float v = vals[c];
        float4 vv = make_float4(v, v, v, v);
        float* o = out + (size_t)c * HW + base;
        ((float4*)o)[0] = vv;
        ((float4*)o)[1] = vv;
    }
}

extern "C" void kernel_launch(void* const* d_in, const int* in_sizes, int n_in,
                              void* d_out, int out_size, void* d_ws, size_t ws_size,
                              hipStream_t stream) {
    const float* rgb = (const float*)d_in[0];
    float* out = (float*)d_out;
    dim3 block(128, 1, 1);                // 2 waves; each wave = 8 cells x 8 parts
    dim3 grid(4096, 1, 1);                // 16 strips x 256 rows (swizzled)
    hipLaunchKernelGGL(pixel_effect_kernel, grid, block, 0, stream, rgb, out);
}

// Round 18
// 28.796 us; speedup vs baseline: 1.0926x; 1.0926x over previous
//
#include <hip/hip_runtime.h>

// PixelEffectModule: 8-bin intensity histogram over 11x11 windows at stride 8,
// argmax bin, output that bin's mean RGB, upsampled 8x8.
// Input: rgb (1,3,2048,2048) fp32 in [0,255). Output: (1,3,2048,2048) fp32.
//
// R18 = R14's green schedule (stage -> drain -> two-pass nibble compute) at
// MAX stream granularity + corrected bank swizzle:
//  - single-wave 64-thread WGs, one 8-cell tile (8 cells x 8 row-band parts
//    = R15's verified mapping). LDS 10,240 B -> 16 WG/CU (2x R14's streams).
//    Zero barriers: drain = wave-local vmcnt(0); reduces = shfl_xor(8/16/32).
//  - bank fix (4th-attempt algebra, both terms): CPR=19 (odd) rotates row
//    bases 3r mod 8 (CPR=34's 2r mod 8 paired quarters on {0,4} -> measured
//    944K-1.58M conflicts); in-row swz(c)=c^((c>>3)&1) (involution on
//    [0,19)) makes any 8-lane stride-2 read span the 8-chunk parity
//    boundary -> 8 lanes on 8 distinct bank groups. Worst case <=2-way.
//  - math path byte-identical to R14/R15 (packed-u64 counts, nibble cache,
//    argmax first-max, predicated-FMA pass 2, row writes).
// Tripwires: absmax != 0 -> revert; conflicts still >500K -> algebra wrong
// again; dur >= 25 us -> structural plateau.

#define Wd 2048
#define HW (2048 * 2048)
#define CPR 19              // 16B chunks per staged row (76 floats, ODD)
#define CPC (11 * CPR)      // 209 chunks per channel
#define NCHK (3 * CPC)      // 627 chunks per tile
#define SLOTS 640           // 10 DMA iters x 64 lanes (13 pad slots)

typedef unsigned int u32;
typedef unsigned long long u64;
typedef float f32x4 __attribute__((ext_vector_type(4)));

// correctly-rounded t/3 (Markstein), 3 ops vs ~9-inst div expansion
__device__ __forceinline__ float div3(float t) {
    const float c = 0x1.555556p-2f;  // RN(1/3)
    float q0 = t * c;
    float r  = __builtin_fmaf(q0, -3.0f, t);
    return __builtin_fmaf(r, c, q0);
}

// in-row chunk swizzle: involution on [0,19) (identity except [8,16) low-bit
// flip). Any 8-lane stride-2 read crosses the 8-boundary -> full 8-group spread.
__device__ __forceinline__ u32 swz(u32 c) { return c ^ ((c >> 3) & 1u); }

__global__ __launch_bounds__(64, 4)
void pixel_effect_kernel(const float* __restrict__ rgb, float* __restrict__ out) {
    __shared__ float ldsf[SLOTS * 4];   // 10,240 B

    const int lane = threadIdx.x;       // single wave
    const int p  = lane >> 3;           // row-band part 0..7
    const int cl = lane & 7;            // cell within 8-strip

    // XCD swizzle (grid 8192 = 8*1024, bijective): XCD (wgid&7) owns slots
    // [1024*xcd, 1024*xcd+1024) = 4 full strip-columns (vertical neighbors
    // share 3 halo rows -> L2 hits within the XCD).
    u32 wgid = blockIdx.x;
    u32 slot = (wgid & 7u) * 1024u + (wgid >> 3);
    const int strip = (int)(slot >> 8);      // x-strip 0..31
    const int oy    = (int)(slot & 255u);    // cell row
    const int ox    = strip * 8 + cl;

    const int xstart = strip ? (strip * 64 - 8) : 0;  // 76-float staged span
    const int ytop   = oy * 8 - 5;

    // ---- DMA stage: 627 chunks global -> LDS (linear dest, pre-swz src) ----
#pragma unroll
    for (int it = 0; it < 10; ++it) {
        u32 cbase = (u32)it * 64u;                      // wave-uniform
        u32 c = cbase + (u32)lane;
        c = c < (NCHK - 1) ? c : (NCHK - 1);            // clamp -> junk to pad
        u32 ch  = (c >= 2u * CPC) ? 2u : (c >= (u32)CPC ? 1u : 0u);
        u32 rem = c - ch * (u32)CPC;
        u32 row = rem / CPR;
        u32 wph = rem - row * CPR;                      // physical chunk-in-row
        u32 wlog = swz(wph);                            // logical chunk to fetch
        int y = ytop + (int)row; y = y < 0 ? 0 : y;     // clamped rows unread
        long o = (long)ch * HW + (long)y * Wd
               + (long)(xstart + (int)(wlog * 4u));
        long omax = 3L * HW - 4;                        // strip-31 halo clamp
        o = o < omax ? o : omax;                        // (clamped chunk unread)
        float* ldst = &ldsf[cbase * 4u];                // wave-uniform base
        __builtin_amdgcn_global_load_lds(
            (const __attribute__((address_space(1))) void*)(rgb + o),
            (__attribute__((address_space(3))) void*)ldst, 16, 0, 0);
    }
    // wave-local drain; memory-clobber asm orders the following ds_reads
    asm volatile("s_waitcnt vmcnt(0)" ::: "memory");
    __builtin_amdgcn_sched_barrier(0);

    // slot j maps row-local x = lx_off + j. Interior: j in [3,13]; ox==0:
    // j in [0,5]. 16-float read [lx_off, lx_off+16) always within the row.
    const int lx_off = (ox == 0) ? 0 : (8 * ox - 8 - xstart);  // = 8*cl (-8 @s0)
    const int w0     = lx_off >> 2;                            // chunk index
    const u32 vmask  = (ox == 0) ? 0x003Fu : 0x3FF8u;
    const int rs = (p < 3) ? 2 * p : (3 + p);  // first window-row of this part
    const int nr = (p < 3) ? 2 : 1;            // rows: 2,2,2,1,1,1,1,1

#define LOADROW(dst, chn, rr)                                                   \
    {                                                                           \
        int rb_ = ((chn) * 11 + (rr)) * CPR;                                    \
        *(f32x4*)((dst) + 0)  = *(const f32x4*)&ldsf[(u32)(rb_ + swz(w0+0))*4u];\
        *(f32x4*)((dst) + 4)  = *(const f32x4*)&ldsf[(u32)(rb_ + swz(w0+1))*4u];\
        *(f32x4*)((dst) + 8)  = *(const f32x4*)&ldsf[(u32)(rb_ + swz(w0+2))*4u];\
        *(f32x4*)((dst) + 12) = *(const f32x4*)&ldsf[(u32)(rb_ + swz(w0+3))*4u];\
    }

    // ---- pass 1: bin pixels, packed byte counts + nibble cache ----
    u64 c64 = 0;
    u32 nbl[2], nbh[2];
#pragma unroll
    for (int k = 0; k < 2; ++k) {
        nbl[k] = 0xFFFFFFFFu; nbh[k] = 0xFFFFFFFFu;
        int r = rs + k;
        int y = ytop + r;
        if (k < nr && y >= 0) {
            float vR[16], vG[16], vB[16];
            LOADROW(vR, 0, r) LOADROW(vG, 1, r) LOADROW(vB, 2, r)
            u32 bl = 0, bh = 0;
#pragma unroll
            for (int j = 0; j < 14; ++j) {
                float m = div3(vR[j] + vG[j] + vB[j]);
                u32 bin = (u32)(m * 0.03125f);     // trunc(mean/32), exact
                u32 valid = (vmask >> j) & 1u;
                c64 += (u64)valid << (bin << 3);
                u32 binv = valid ? bin : 15u;      // 15 matches no bin
                if (j < 8) bl |= binv << (4 * j);
                else       bh |= binv << (4 * (j - 8));
            }
            nbl[k] = bl; nbh[k] = bh;
        }
    }

    // ---- reduce counts across the 8 parts (lane bits 3,4,5) ----
    c64 += __shfl_xor(c64, 8);
    c64 += __shfl_xor(c64, 16);
    c64 += __shfl_xor(c64, 32);

    u32 lo = (u32)c64, hi = (u32)(c64 >> 32);
    u32 best = 0, bc = lo & 0xFFu;
#pragma unroll
    for (int b = 1; b < 8; ++b) {
        u32 cb = ((b < 4 ? lo : hi) >> ((b & 3) * 8)) & 0xFFu;
        bool t = cb > bc;
        bc   = t ? cb : bc;
        best = t ? (u32)b : best;
    }

    // ---- pass 2: re-read LDS (conflict-free), sum winning bin via nibbles ----
    float sr = 0.f, sg = 0.f, sb = 0.f;
#pragma unroll
    for (int k = 0; k < 2; ++k) {
        int r = rs + k;
        int y = ytop + r;
        if (k < nr && y >= 0) {
            float vR[16], vG[16], vB[16];
            LOADROW(vR, 0, r) LOADROW(vG, 1, r) LOADROW(vB, 2, r)
            u32 bl = nbl[k], bh = nbh[k];
#pragma unroll
            for (int j = 0; j < 14; ++j) {
                u32 bin = ((j < 8) ? (bl >> (4 * j))
                                   : (bh >> (4 * (j - 8)))) & 0xFu;
                float hm = (bin == best) ? 1.0f : 0.0f;
                sr = __builtin_fmaf(hm, vR[j], sr);
                sg = __builtin_fmaf(hm, vG[j], sg);
                sb = __builtin_fmaf(hm, vB[j], sb);
            }
        }
    }
    sr += __shfl_xor(sr, 8); sr += __shfl_xor(sr, 16); sr += __shfl_xor(sr, 32);
    sg += __shfl_xor(sg, 8); sg += __shfl_xor(sg, 16); sg += __shfl_xor(sg, 32);
    sb += __shfl_xor(sb, 8); sb += __shfl_xor(sb, 16); sb += __shfl_xor(sb, 32);

    float fbc = (float)bc;
    float orv = sr / fbc, ogv = sg / fbc, obv = sb / fbc;

    // ---- write: part p owns row p of the 8x8 block, 2x float4 per channel ----
    size_t base = (size_t)(oy * 8 + p) * Wd + (size_t)(ox * 8);
    float vals[3] = { orv, ogv, obv };
#pragma unroll
    for (int c = 0; c < 3; ++c) {
        float v = vals[c];
        float4 vv = make_float4(v, v, v, v);
        float* o = out + (size_t)c * HW + base;
        ((float4*)o)[0] = vv;
        ((float4*)o)[1] = vv;
    }
}

extern "C" void kernel_launch(void* const* d_in, const int* in_sizes, int n_in,
                              void* d_out, int out_size, void* d_ws, size_t ws_size,
                              hipStream_t stream) {
    const float* rgb = (const float*)d_in[0];
    float* out = (float*)d_out;
    dim3 block(64, 1, 1);                 // 1 wave = 1 tile; zero barriers
    dim3 grid(8192, 1, 1);                // 32 strips x 256 rows (XCD-swizzled)
    hipLaunchKernelGGL(pixel_effect_kernel, grid, block, 0, stream, rgb, out);
}

// Round 19
// 25.752 us; speedup vs baseline: 1.2217x; 1.1182x over previous
//
#include <hip/hip_runtime.h>

// PixelEffectModule: 8-bin intensity histogram over 11x11 windows at stride 8,
// argmax bin, output that bin's mean RGB, upsampled 8x8.
// Input: rgb (1,3,2048,2048) fp32 in [0,255). Output: (1,3,2048,2048) fp32.
//
// R19 = R14 green (25.2 us, absmax 0.0) + ONE delta: exact bank-conflict fix.
// R14's ds_read_b128 spans 4 quarters reading different rows at stride-2
// chunks; CPR=34 (mod 8 = 2) put all 64 lanes on bank-groups {0,2,4,6} =
// 16 lanes/group (floor is 8) -> measured 1.58M conflict cycles. Fix:
//  - LDS row PITCH 35 chunks (mod 8 = 3), decoupled from the 34 staged
//    chunks by one junk pad slot per row (slot wp==34; written with junk,
//    never read; DMA dest stays linear per instruction).
//  - pair-swap swizzle swz(c)=c^((c>>1)&1) (involution) on DMA source
//    chunk-in-row and on the read index: quarter's stride-2 reads spread
//    over {0,3,4,7}+rb, and pitch-35 row rotation tiles all 8 groups with
//    exactly 8 lanes each (enumerated for every row-set the waves issue).
// Everything else byte-identical to R14: 16-cell tiles, 128-thread WGs,
// 9->10 DMA iters, one __syncthreads drain, XCD swizzle, two-pass nibble
// math, shfl(16/32)+LDS reduces, row writes.
// Tripwires: absmax != 0 -> revert; conflicts still >500K -> algebra wrong
// AGAIN (stop swizzling forever); dur >= 25 -> LDS not critical, plateau.

#define Wd 2048
#define HW (2048 * 2048)
#define CPR 34              // staged 16B chunks per row (136 floats)
#define PITCH 35            // LDS row pitch in chunks (pad slot wp==34)
#define SPC (11 * PITCH)    // 385 padded slots per channel
#define NSLOT (3 * SPC)     // 1155 padded slots per tile
#define ITERS 10            // 10 x 128 = 1280 slots (125 tail-pad)

typedef unsigned int u32;
typedef unsigned long long u64;
typedef float f32x4 __attribute__((ext_vector_type(4)));

// correctly-rounded t/3 (Markstein), 3 ops vs ~9-inst div expansion
__device__ __forceinline__ float div3(float t) {
    const float c = 0x1.555556p-2f;  // RN(1/3)
    float q0 = t * c;
    float r  = __builtin_fmaf(q0, -3.0f, t);
    return __builtin_fmaf(r, c, q0);
}

// pair-swap swizzle: involution (2<->3, 6<->7, ...); identity on 32,33
__device__ __forceinline__ u32 swz(u32 c) { return c ^ ((c >> 1) & 1u); }

__global__ __launch_bounds__(128, 4)
void pixel_effect_kernel(const float* __restrict__ rgb, float* __restrict__ out) {
    __shared__ float  ldsf[1280 * 4];   // 20.5 KB staged tile (pitch-padded)
    __shared__ u64    sc[2][16];
    __shared__ float4 ss[2][16];

    const int tid  = threadIdx.x;       // 0..127
    const int lane = tid & 63;
    const int w    = tid >> 6;          // wave 0..1
    const int qid  = (tid >> 4) & 3;    // quarter within wave
    const int cl   = tid & 15;          // cell within 16-strip
    const int p    = w * 4 + qid;       // row-band part 0..7

    // XCD swizzle (grid 4096 = 8*512, bijective): XCD (wgid&7) owns slots
    // [512*xcd, 512*xcd+512) = 32 contiguous cell-rows.
    u32 wgid = blockIdx.x;
    u32 slot = (wgid & 7u) * 512u + (wgid >> 3);
    const int oy = (int)(slot >> 4);
    const int tx = (int)(slot & 15u);
    const int ox = tx * 16 + cl;

    const int xstart = tx ? (tx * 128 - 8) : 0;   // staged 136-float span
    const int ytop   = oy * 8 - 5;

    // ---- DMA stage: 1155 padded slots -> LDS (linear dest, swz source) ----
#pragma unroll
    for (int it = 0; it < ITERS; ++it) {
        u32 cbase = (u32)it * 128u + (u32)(tid & ~63);  // wave-uniform
        u32 s = cbase + (u32)lane;
        s = s < (NSLOT - 1) ? s : (NSLOT - 1);          // tail -> last pad slot
        u32 ch  = s / SPC;
        u32 rem = s - ch * SPC;
        u32 row = rem / PITCH;
        u32 wp  = rem - row * PITCH;                    // slot-in-row (0..34)
        u32 wlog = (wp == 34u) ? 33u : swz(wp);         // pad slot -> junk src
        int y = ytop + (int)row; y = y < 0 ? 0 : y;     // clamped rows unread
        const float* gsrc = rgb + (size_t)ch * HW + (size_t)y * Wd
                          + (size_t)(xstart + (int)(wlog * 4u));
        float* ldst = &ldsf[cbase * 4u];                // wave-uniform base
        __builtin_amdgcn_global_load_lds(
            (const __attribute__((address_space(1))) void*)gsrc,
            (__attribute__((address_space(3))) void*)ldst, 16, 0, 0);
    }
    __syncthreads();   // single vmcnt drain (R14 green schedule)

    // slot j maps row-local x = lx_off + j. Interior: j in [3,13]; ox==0:
    // j in [0,5]. 16-float read [lx_off, lx_off+16) always within the row.
    const int lx_off = (ox == 0) ? 0 : (8 * ox - 8 - xstart);  // mult of 8
    const int w0     = lx_off >> 2;                            // chunk index
    const u32 vmask  = (ox == 0) ? 0x003Fu : 0x3FF8u;
    const int rs = (p < 3) ? 2 * p : (3 + p);  // first window-row of this part
    const int nr = (p < 3) ? 2 : 1;            // rows: 2,2,2,1,1,1,1,1

#define LOADROW(dst, chn, rr)                                                    \
    {                                                                            \
        int rb_ = ((chn) * 11 + (rr)) * PITCH;                                   \
        *(f32x4*)((dst) + 0)  = *(const f32x4*)&ldsf[(u32)(rb_ + swz(w0+0))*4u]; \
        *(f32x4*)((dst) + 4)  = *(const f32x4*)&ldsf[(u32)(rb_ + swz(w0+1))*4u]; \
        *(f32x4*)((dst) + 8)  = *(const f32x4*)&ldsf[(u32)(rb_ + swz(w0+2))*4u]; \
        *(f32x4*)((dst) + 12) = *(const f32x4*)&ldsf[(u32)(rb_ + swz(w0+3))*4u]; \
    }

    // ---- pass 1: bin pixels, packed byte counts + nibble cache ----
    u64 c64 = 0;
    u32 nbl[2], nbh[2];
#pragma unroll
    for (int k = 0; k < 2; ++k) {
        nbl[k] = 0xFFFFFFFFu; nbh[k] = 0xFFFFFFFFu;
        int r = rs + k;
        int y = ytop + r;                      // uniform per quarter
        if (k < nr && y >= 0) {
            float vR[16], vG[16], vB[16];
            LOADROW(vR, 0, r) LOADROW(vG, 1, r) LOADROW(vB, 2, r)
            u32 bl = 0, bh = 0;
#pragma unroll
            for (int j = 0; j < 14; ++j) {
                float m = div3(vR[j] + vG[j] + vB[j]);
                u32 bin = (u32)(m * 0.03125f);     // trunc(mean/32), exact
                u32 valid = (vmask >> j) & 1u;
                c64 += (u64)valid << (bin << 3);
                u32 binv = valid ? bin : 15u;      // 15 matches no bin
                if (j < 8) bl |= binv << (4 * j);
                else       bh |= binv << (4 * (j - 8));
            }
            nbl[k] = bl; nbh[k] = bh;
        }
    }

    // ---- reduce counts: 4 parts within wave (xor16, xor32), then 2 waves ----
    c64 += __shfl_xor(c64, 16);
    c64 += __shfl_xor(c64, 32);
    if (qid == 0) sc[w][cl] = c64;
    __syncthreads();

    u64 tot = sc[0][cl] + sc[1][cl];           // bytes <= 121: no carries
    u32 lo = (u32)tot, hi = (u32)(tot >> 32);
    u32 best = 0, bc = lo & 0xFFu;
#pragma unroll
    for (int b = 1; b < 8; ++b) {
        u32 cb = ((b < 4 ? lo : hi) >> ((b & 3) * 8)) & 0xFFu;
        bool t = cb > bc;
        bc   = t ? cb : bc;
        best = t ? (u32)b : best;
    }

    // ---- pass 2: re-read LDS (now conflict-balanced), sum winning bin ----
    float sr = 0.f, sg = 0.f, sb = 0.f;
#pragma unroll
    for (int k = 0; k < 2; ++k) {
        int r = rs + k;
        int y = ytop + r;
        if (k < nr && y >= 0) {
            float vR[16], vG[16], vB[16];
            LOADROW(vR, 0, r) LOADROW(vG, 1, r) LOADROW(vB, 2, r)
            u32 bl = nbl[k], bh = nbh[k];
#pragma unroll
            for (int j = 0; j < 14; ++j) {
                u32 bin = ((j < 8) ? (bl >> (4 * j))
                                   : (bh >> (4 * (j - 8)))) & 0xFu;
                float hm = (bin == best) ? 1.0f : 0.0f;
                sr = __builtin_fmaf(hm, vR[j], sr);
                sg = __builtin_fmaf(hm, vG[j], sg);
                sb = __builtin_fmaf(hm, vB[j], sb);
            }
        }
    }
    sr += __shfl_xor(sr, 16);  sr += __shfl_xor(sr, 32);
    sg += __shfl_xor(sg, 16);  sg += __shfl_xor(sg, 32);
    sb += __shfl_xor(sb, 16);  sb += __shfl_xor(sb, 32);

    if (qid == 0) ss[w][cl] = make_float4(sr, sg, sb, 0.f);
    __syncthreads();

    float4 s0 = ss[0][cl], s1 = ss[1][cl];
    float fbc = (float)bc;
    float orv = (s0.x + s1.x) / fbc;
    float ogv = (s0.y + s1.y) / fbc;
    float obv = (s0.z + s1.z) / fbc;

    // ---- write: part p owns row p of the 8x8 block, 2x float4 per channel ----
    size_t base = (size_t)(oy * 8 + p) * Wd + (size_t)(ox * 8);
    float vals[3] = { orv, ogv, obv };
#pragma unroll
    for (int c = 0; c < 3; ++c) {
        float v = vals[c];
        float4 vv = make_float4(v, v, v, v);
        float* o = out + (size_t)c * HW + base;
        ((float4*)o)[0] = vv;
        ((float4*)o)[1] = vv;
    }
}

extern "C" void kernel_launch(void* const* d_in, const int* in_sizes, int n_in,
                              void* d_out, int out_size, void* d_ws, size_t ws_size,
                              hipStream_t stream) {
    const float* rgb = (const float*)d_in[0];
    float* out = (float*)d_out;
    dim3 block(128, 1, 1);                // 2 waves; wave = 16 cells x 4 parts
    dim3 grid(4096, 1, 1);                // 16 strips/cell-row x 256 rows (swizzled)
    hipLaunchKernelGGL(pixel_effect_kernel, grid, block, 0, stream, rgb, out);
}